// Round 8
// baseline (282.187 us; speedup 1.0000x reference)
//
#include <hip/hip_runtime.h>
#include <hip/hip_bf16.h>
#include <math.h>

#define N_NODES 3200
#define E_EDGES 50000
#define RBFN 16
#define HID 128
#define NS 32
#define NV 16
#define DD 80
#define WNUM 2304
#define CUTF 5.0f
#define EPSF 1e-8f

#define A1C 0.125f                  // 1/sqrt(2*NS)
#define A2C 0.17677669529663687f    // 1/sqrt(2*NV)
#define A3C 0.125f
#define A4C 0.17677669529663687f
#define A2ISQ 0.10206207261596575f  // A2C / sqrt(3)

typedef __attribute__((ext_vector_type(4))) float f32x4;
typedef __attribute__((ext_vector_type(8))) short bf16x8;

__device__ __forceinline__ float sigm(float x) { return 1.0f / (1.0f + __expf(-x)); }
__device__ __forceinline__ float silu_f(float x) { return x * sigm(x); }

__device__ __forceinline__ short bf16r(float x) {
    union { float f; unsigned u; } v; v.f = x;
    unsigned r = (v.u + 0x7fffu + ((v.u >> 16) & 1u)) >> 16;
    return (short)r;
}
__device__ __forceinline__ float b2f(unsigned short s) {
    union { float f; unsigned u; } v; v.u = ((unsigned)s) << 16; return v.f;
}

// ---------------- CSR sort helpers ----------------------------------------------
__global__ void k_scan(const int* __restrict__ hist, int* __restrict__ start) {
    __shared__ int part[256];
    int t = threadIdx.x;
    int loc[13];
    int s = 0;
#pragma unroll
    for (int j = 0; j < 13; j++) {
        int idx = t * 13 + j;
        int v = (idx < N_NODES) ? hist[idx] : 0;
        loc[j] = s; s += v;
    }
    part[t] = s;
    __syncthreads();
    for (int off = 1; off < 256; off <<= 1) {
        int v = part[t];
        int add = (t >= off) ? part[t - off] : 0;
        __syncthreads();
        part[t] = v + add;
        __syncthreads();
    }
    int pre = (t == 0) ? 0 : part[t - 1];
#pragma unroll
    for (int j = 0; j < 13; j++) {
        int idx = t * 13 + j;
        if (idx < N_NODES) start[idx] = pre + loc[j];
    }
    if (t == 255) start[N_NODES] = part[255];
}

__global__ void k_scatter(const int* __restrict__ edst, const int* __restrict__ start,
                          int* __restrict__ cur, int* __restrict__ perm) {
    int e = blockIdx.x * 256 + threadIdx.x;
    if (e < E_EDGES) {
        int d = edst[e];
        int pos = start[d] + atomicAdd(&cur[d], 1);
        perm[pos] = e;
    }
}

// ---------------- K_prep0: mw2 -> frag-linear bf16 (must precede k_front) -------
__global__ void k_prep0(const float* __restrict__ mw2, __hip_bfloat16* __restrict__ mw2f) {
    __shared__ __hip_bfloat16 st[2048];
    int t = blockIdx.x, tid = threadIdx.x;
    for (int idx = tid; idx < 2048; idx += 256) {
        int k = idx >> 4, c = idx & 15;
        float v = mw2[k * HID + t * 16 + c];
        int kk = k >> 5, q4 = (k >> 3) & 3, j = k & 7;
        st[kk * 512 + (q4 * 16 + c) * 8 + j] = __float2bfloat16(v);
    }
    __syncthreads();
    ((bf16x8*)(mw2f + t * 2048))[tid] = ((const bf16x8*)st)[tid];
}

// ---------------- K_front: edge MLP (fused) + mw3 prep + norm + hist ------------
__global__ __launch_bounds__(256) void k_front(
    const float* __restrict__ rbf, const float* __restrict__ elen,
    const int* __restrict__ edst,
    const float* __restrict__ mw1, const float* __restrict__ mb1,
    const float* __restrict__ gw1, const float* __restrict__ gb1,
    const float* __restrict__ gw2, const float* __restrict__ gb2,
    const float* __restrict__ mb2, const __hip_bfloat16* __restrict__ mw2f,
    const float* __restrict__ mw3, const float* __restrict__ mb3,
    const float* __restrict__ x, const float* __restrict__ nw, const float* __restrict__ nb,
    float* __restrict__ ewg, __hip_bfloat16* __restrict__ h2b,
    __hip_bfloat16* __restrict__ mw3f, __hip_bfloat16* __restrict__ biasf,
    float* __restrict__ xn, int* __restrict__ hist) {
    __shared__ __align__(16) char smem[16640];
    int b = blockIdx.x, tid = threadIdx.x;
    if (b < 782) {
        __hip_bfloat16* h1l = (__hip_bfloat16*)smem;   // [64][128]
        int wid = __builtin_amdgcn_readfirstlane(tid >> 6);
        int lane = tid & 63;
        int base = b * 64;
        int eb = base + wid * 16;
        // ---- mlp1 (wave: 16 edges x 128 ch) ----
        {
            int c0 = lane, c1 = 64 + lane;
            float t0[16], t1[16], g0[16], g1[16];
            float b0 = mb1[c0], b1 = mb1[c1], gb0v = gb1[c0], gb1v = gb1[c1];
#pragma unroll
            for (int e = 0; e < 16; e++) { t0[e] = b0; t1[e] = b1; g0[e] = gb0v; g1[e] = gb1v; }
#pragma unroll
            for (int r = 0; r < RBFN; r++) {
                float w0 = mw1[r * HID + c0], w1 = mw1[r * HID + c1];
                float v0 = gw1[r * HID + c0], v1 = gw1[r * HID + c1];
#pragma unroll
                for (int e = 0; e < 16; e++) {
                    int ee = eb + e; if (ee >= E_EDGES) ee = E_EDGES - 1;
                    float rv = rbf[ee * RBFN + r];
                    t0[e] += rv * w0; t1[e] += rv * w1;
                    g0[e] += rv * v0; g1[e] += rv * v1;
                }
            }
            float q0 = gw2[c0], q1 = gw2[c1];
            float gb2v = gb2[0];
#pragma unroll
            for (int e = 0; e < 16; e++) {
                int le = wid * 16 + e;
                h1l[le * 128 + c0] = __float2bfloat16(silu_f(t0[e]));
                h1l[le * 128 + c1] = __float2bfloat16(silu_f(t1[e]));
                float p = silu_f(g0[e]) * q0 + silu_f(g1[e]) * q1;
                p += __shfl_xor(p, 1);  p += __shfl_xor(p, 2);  p += __shfl_xor(p, 4);
                p += __shfl_xor(p, 8);  p += __shfl_xor(p, 16); p += __shfl_xor(p, 32);
                if (lane == 0 && eb + e < E_EDGES) {
                    float len = elen[eb + e];
                    float cut = (len <= CUTF) ? 0.5f * (cosf(3.14159265358979f * len / CUTF) + 1.0f) : 0.f;
                    ewg[eb + e] = cut * sigm(p + gb2v);
                }
            }
        }
        __syncthreads();
        // ---- mlp2 (wave: 16 edges, MFMA vs mw2f) ----
        {
            int q4 = lane >> 4, l15 = lane & 15;
            int le = wid * 16 + l15;
            bf16x8 af[4];
#pragma unroll
            for (int kk = 0; kk < 4; kk++)
                af[kk] = *(const bf16x8*)(h1l + le * 128 + kk * 32 + q4 * 8);
            const f32x4 zf = {0.f, 0.f, 0.f, 0.f};
#pragma unroll
            for (int ct = 0; ct < 8; ct++) {
                f32x4 acc = zf;
#pragma unroll
                for (int kk = 0; kk < 4; kk++) {
                    bf16x8 bw = *(const bf16x8*)(mw2f + (ct * 4 + kk) * 512 + lane * 8);
                    acc = __builtin_amdgcn_mfma_f32_16x16x32_bf16(af[kk], bw, acc, 0, 0, 0);
                }
                float bias = mb2[ct * 16 + l15];
#pragma unroll
                for (int r = 0; r < 4; r++) {
                    int ge = base + wid * 16 + q4 * 4 + r;
                    if (ge < E_EDGES)
                        h2b[ge * HID + ct * 16 + l15] = __float2bfloat16(silu_f(acc[r] + bias));
                }
            }
        }
    } else if (b < 927) {
        int b2 = b - 782;
        __hip_bfloat16* st = (__hip_bfloat16*)smem;
        if (b2 < 144) {
            for (int idx = tid; idx < 2048; idx += 256) {
                int k = idx >> 4, c = idx & 15;
                float v = mw3[k * WNUM + b2 * 16 + c];
                int kk = k >> 5, q4 = (k >> 3) & 3, j = k & 7;
                st[kk * 512 + (q4 * 16 + c) * 8 + j] = __float2bfloat16(v);
            }
            __syncthreads();
            ((bf16x8*)(mw3f + b2 * 2048))[tid] = ((const bf16x8*)st)[tid];
        } else {
            for (int idx = tid; idx < 3072; idx += 256) {
                float val;
                if (idx < 1024) {
                    int oh = idx >> 9, l = (idx >> 3) & 63, j = idx & 7;
                    int o = oh * 16 + (l & 15), i = (l >> 4) * 8 + j;
                    val = mb3[i * 32 + o];
                } else if (idx < 2048) {
                    int t = idx - 1024;
                    int oh = t >> 9, l = (t >> 3) & 63, j = t & 7;
                    int o = oh * 16 + (l & 15), i = (l >> 4) * 8 + j;
                    val = (i < 16) ? mb3[1024 + i * 32 + o] : 0.f;
                } else if (idx < 2560) {
                    int t = idx - 2048;
                    int l = t >> 3, j = t & 7;
                    int o = l & 15, i = (l >> 4) * 8 + j;
                    val = mb3[1536 + i * 16 + o];
                } else {
                    int t = idx - 2560;
                    int l = t >> 3, j = t & 7;
                    int o = l & 15, i = (l >> 4) * 8 + j;
                    val = (i < 16) ? mb3[2048 + i * 16 + o] : 0.f;
                }
                biasf[idx] = __float2bfloat16(val);
            }
        }
    } else if (b < 1727) {
        // irrep norm: 4 nodes per block
        float* row = (float*)smem;   // [4][80]
        int sub = tid >> 6, t = tid & 63;
        int n = (b - 927) * 4 + sub;
        float* rw = row + sub * 80;
        const float* xr = x + n * DD;
        rw[t] = xr[t];
        if (t < 16) rw[64 + t] = xr[64 + t];
        __syncthreads();
        float mean = 0.f;
#pragma unroll
        for (int i = 0; i < NS; i++) mean += rw[i];
        mean *= (1.0f / NS);
        float var = 0.f;
#pragma unroll
        for (int i = 0; i < NS; i++) { float d = rw[i] - mean; var += d * d; }
        var *= (1.0f / NS);
        float inv = rsqrtf(var + EPSF);
        if (t < NS) xn[n * DD + t] = (rw[t] - mean) * inv * nw[t] + nb[t];
        if (t < 48) {
            int j = t / 3;
            float v0 = rw[NS + 3 * j], v1 = rw[NS + 3 * j + 1], v2 = rw[NS + 3 * j + 2];
            float rms = sqrtf((v0 * v0 + v1 * v1 + v2 * v2) * (1.0f / 3.0f) + EPSF);
            xn[n * DD + NS + t] = rw[NS + t] / rms * nw[NS + t] + nb[NS + t];
        }
    } else {
        int e = (b - 1727) * 256 + tid;
        if (e < E_EDGES) atomicAdd(&hist[edst[e]], 1);
    }
}

// -------- K_msg: LDS-shared A-chunks, 4 waves x 32 edges, BALANCED role split ---
// roleA (even blockIdx): chunks 0..36  -> S partial (+ bias) + den
// roleB (odd  blockIdx): chunks 36..72 -> S partial (w2 tail) + V channels
// S channels are dual-writer -> always atomicAdd; den (A-only) and V (B-only)
// keep interior-store. Pipeline per chunk: barrier -> ds_write next buf ->
// issue global prefetch -> compute (loads get a full compute phase before the
// next barrier's vmcnt(0) drain).
__global__ __launch_bounds__(256) void k_msg(
    const float* __restrict__ xn, const __hip_bfloat16* __restrict__ h2b,
    const float* __restrict__ ewg, const int* __restrict__ esrc,
    const int* __restrict__ edst, const int* __restrict__ perm,
    const float* __restrict__ esh,
    const __hip_bfloat16* __restrict__ mw3f, const __hip_bfloat16* __restrict__ biasf,
    const int* __restrict__ startp, float* __restrict__ agg, float* __restrict__ den) {
    __shared__ __align__(16) char pool[46080];
    unsigned short (*xng)[82]  = (unsigned short(*)[82])(pool);
    unsigned short (*innr)[16] = (unsigned short(*)[16])(pool + 20992);
    f32x4* lb0  = (f32x4*)(pool + 25088);
    f32x4* lb1  = (f32x4*)(pool + 25088 + 8192);
    float (*sh1l)[4] = (float(*)[4])(pool + 41472);
    float* sh0l = (float*)(pool + 43520);
    float* ewl  = (float*)(pool + 44032);
    int* dstl   = (int*)(pool + 44544);
    int* srcl   = (int*)(pool + 45056);
    int* gel    = (int*)(pool + 45568);
    float* msgl = (float*)(pool);              // [128][48] alias (epilogue only)

    const int tid = threadIdx.x;
    const int wid = __builtin_amdgcn_readfirstlane(tid >> 6);
    const int lane = tid & 63;
    const int q4 = lane >> 4;
    const int l15 = lane & 15;
    const int ib = q4 * 8;
    const int role = blockIdx.x & 1;
    const int e0 = (blockIdx.x >> 1) * 128;

    if (tid < 128) {
        int slot = e0 + tid;
        bool v = slot < E_EDGES;
        int ge = v ? perm[slot] : 0;
        gel[tid] = ge;
        srcl[tid] = esrc[ge];
        dstl[tid] = v ? edst[ge] : -1;
        ewl[tid] = v ? ewg[ge] : 0.f;
        sh0l[tid] = esh[ge * 4];
        sh1l[tid][0] = esh[ge * 4 + 1];
        sh1l[tid][1] = esh[ge * 4 + 2];
        sh1l[tid][2] = esh[ge * 4 + 3];
    }
    __syncthreads();
    for (int idx = tid; idx < 128 * 80; idx += 256) {
        int e = idx / 80, q = idx - e * 80;
        xng[e][q] = (unsigned short)bf16r(xn[srcl[e] * 80 + q]);
    }
    __syncthreads();
    for (int idx = tid; idx < 128 * 16; idx += 256) {
        int e = idx >> 4, i = idx & 15;
        float d = b2f(xng[e][32 + 3 * i]) * sh1l[e][0]
                + b2f(xng[e][32 + 3 * i + 1]) * sh1l[e][1]
                + b2f(xng[e][32 + 3 * i + 2]) * sh1l[e][2];
        innr[e][i] = (unsigned short)bf16r(A2ISQ * d);
    }
    __syncthreads();

    // ---------------- per-wave prologue ----------------
    int el[2] = { wid * 32 + l15, wid * 32 + 16 + l15 };
    bf16x8 hfr[2][4];
#pragma unroll
    for (int et = 0; et < 2; et++) {
        int ge = gel[el[et]];
        const __hip_bfloat16* hr = h2b + ge * HID;
#pragma unroll
        for (int kk = 0; kk < 4; kk++)
            hfr[et][kk] = *(const bf16x8*)(hr + kk * 32 + ib);
    }
    const f32x4 zf = {0.f, 0.f, 0.f, 0.f};
    float f1[2], f4e[2];
    f32x4 msgS[2][2], q3[2], qv[3][2];
#pragma unroll
    for (int et = 0; et < 2; et++) {
        f1[et] = A1C * sh0l[el[et]];
        f4e[et] = A4C * sh0l[el[et]];
        msgS[0][et] = zf; msgS[1][et] = zf;
        q3[et] = zf; qv[0][et] = zf; qv[1][et] = zf; qv[2][et] = zf;
    }
    if (role == 0) {
        // S bias via MFMA (added exactly once, by roleA)
#pragma unroll
        for (int et = 0; et < 2; et++) {
            bf16x8 p18, p28;
#pragma unroll
            for (int j = 0; j < 8; j++) {
                p18[j] = bf16r(b2f(xng[el[et]][ib + j]) * f1[et]);
                p28[j] = (ib + j < 16) ? (short)innr[el[et]][ib + j] : (short)0;
            }
            bf16x8 ba1a = *(const bf16x8*)(biasf + lane * 8);
            bf16x8 ba1b = *(const bf16x8*)(biasf + 512 + lane * 8);
            bf16x8 ba2a = *(const bf16x8*)(biasf + 1024 + lane * 8);
            bf16x8 ba2b = *(const bf16x8*)(biasf + 1536 + lane * 8);
            f32x4 a0 = __builtin_amdgcn_mfma_f32_16x16x32_bf16(ba1a, p18, zf, 0, 0, 0);
            msgS[0][et] = __builtin_amdgcn_mfma_f32_16x16x32_bf16(ba2a, p28, a0, 0, 0, 0);
            f32x4 a1 = __builtin_amdgcn_mfma_f32_16x16x32_bf16(ba1b, p18, zf, 0, 0, 0);
            msgS[1][et] = __builtin_amdgcn_mfma_f32_16x16x32_bf16(ba2b, p28, a1, 0, 0, 0);
        }
    } else {
        // V bias via MFMA (by roleB)
#pragma unroll
        for (int et = 0; et < 2; et++) {
            bf16x8 xs8;
#pragma unroll
            for (int j = 0; j < 8; j++) xs8[j] = (short)xng[el[et]][ib + j];
            bf16x8 ba3 = *(const bf16x8*)(biasf + 2048 + lane * 8);
            bf16x8 ba4 = *(const bf16x8*)(biasf + 2560 + lane * 8);
            q3[et] = __builtin_amdgcn_mfma_f32_16x16x32_bf16(ba3, xs8, zf, 0, 0, 0);
#pragma unroll
            for (int m = 0; m < 3; m++) {
                bf16x8 t8;
#pragma unroll
                for (int j = 0; j < 8; j++) {
                    int i = ib + j;
                    t8[j] = (i < 16) ? (short)xng[el[et]][32 + 3 * i + m] : (short)0;
                }
                qv[m][et] = __builtin_amdgcn_mfma_f32_16x16x32_bf16(ba4, t8, zf, 0, 0, 0);
            }
        }
    }

    // ---------------- main loop: balanced 36 chunks/role --------------------------
    const f32x4* gsrc = (const f32x4*)mw3f;    // 16B units; chunk = 512 units

    auto compute_chunk = [&](int n, const __hip_bfloat16* bb) {
        f32x4 acc[2][2];
#pragma unroll
        for (int half = 0; half < 2; half++) {
            f32x4 a0 = zf, a1 = zf;
#pragma unroll
            for (int kk = 0; kk < 4; kk++) {
                bf16x8 af = *(const bf16x8*)(bb + ((half * 4 + kk) * 64 + lane) * 8);
                a0 = __builtin_amdgcn_mfma_f32_16x16x32_bf16(af, hfr[0][kk], a0, 0, 0, 0);
                a1 = __builtin_amdgcn_mfma_f32_16x16x32_bf16(af, hfr[1][kk], a1, 0, 0, 0);
            }
            acc[half][0] = a0; acc[half][1] = a1;
        }
        if (n < 32) {
            float p0 = f1[0] * b2f(xng[el[0]][n]);
            float p1 = f1[1] * b2f(xng[el[1]][n]);
#pragma unroll
            for (int half = 0; half < 2; half++)
#pragma unroll
                for (int r = 0; r < 4; r++) {
                    msgS[half][0][r] += p0 * acc[half][0][r];
                    msgS[half][1][r] += p1 * acc[half][1][r];
                }
        } else if (n < 48) {
            float p0 = b2f(innr[el[0]][n - 32]);
            float p1 = b2f(innr[el[1]][n - 32]);
#pragma unroll
            for (int half = 0; half < 2; half++)
#pragma unroll
                for (int r = 0; r < 4; r++) {
                    msgS[half][0][r] += p0 * acc[half][0][r];
                    msgS[half][1][r] += p1 * acc[half][1][r];
                }
        } else if (n < 64) {
#pragma unroll
            for (int half = 0; half < 2; half++) {
                int i = 2 * (n - 48) + half;
                float p0 = b2f(xng[el[0]][i]);
                float p1 = b2f(xng[el[1]][i]);
#pragma unroll
                for (int r = 0; r < 4; r++) {
                    q3[0][r] += p0 * acc[half][0][r];
                    q3[1][r] += p1 * acc[half][1][r];
                }
            }
        } else {
#pragma unroll
            for (int half = 0; half < 2; half++) {
                int i = 2 * (n - 64) + half;
#pragma unroll
                for (int m = 0; m < 3; m++) {
                    float p0 = b2f(xng[el[0]][32 + 3 * i + m]);
                    float p1 = b2f(xng[el[1]][32 + 3 * i + m]);
#pragma unroll
                    for (int r = 0; r < 4; r++) {
                        qv[m][0][r] += p0 * acc[half][0][r];
                        qv[m][1][r] += p1 * acc[half][1][r];
                    }
                }
            }
        }
    };

    const int n0 = role ? 36 : 0;
    const int n1 = role ? 72 : 36;
    f32x4 rg0 = gsrc[n0 * 512 + tid];
    f32x4 rg1 = gsrc[n0 * 512 + 256 + tid];
    {   // stage chunk n0; prefetch chunk n0+1
        f32x4* wb = (n0 & 1) ? lb1 : lb0;
        wb[tid] = rg0; wb[tid + 256] = rg1;
        rg0 = gsrc[(n0 + 1) * 512 + tid];
        rg1 = gsrc[(n0 + 1) * 512 + 256 + tid];
    }
    for (int n = n0; n < n1; n++) {
        __syncthreads();
        if (n + 1 < n1) {
            f32x4* wb = ((n + 1) & 1) ? lb1 : lb0;
            wb[tid] = rg0; wb[tid + 256] = rg1;
            if (n + 2 < n1) {
                rg0 = gsrc[(n + 2) * 512 + tid];
                rg1 = gsrc[(n + 2) * 512 + 256 + tid];
            }
        }
        compute_chunk(n, (const __hip_bfloat16*)((n & 1) ? lb1 : lb0));
    }

    // ---------------- epilogue ---------------------------------------------------
    __syncthreads();   // all waves done reading xng/innr/dbuf
    int cnt = E_EDGES - e0; if (cnt > 128) cnt = 128;
    if (role == 0) {
        // S channels + den
#pragma unroll
        for (int et = 0; et < 2; et++) {
            int le = el[et];
            float ew = ewl[le];
#pragma unroll
            for (int oh = 0; oh < 2; oh++)
#pragma unroll
                for (int r = 0; r < 4; r++)
                    msgl[le * 48 + oh * 16 + q4 * 4 + r] = msgS[oh][et][r] * ew;
        }
        __syncthreads();
        if (tid < 33) {
            int c = tid;
            int cur = dstl[0];
            float acc = 0.f;
            for (int r = 0; r < cnt; r++) {
                int nd = dstl[r];
                if (nd != cur) {
                    if (cur >= 0) {
                        if (c == 32) {
                            bool interior = (startp[cur] >= e0) && (startp[cur + 1] <= e0 + 128);
                            if (interior) den[cur] = acc; else atomicAdd(den + cur, acc);
                        } else {
                            atomicAdd(agg + cur * 80 + c, acc);   // dual-writer with roleB
                        }
                    }
                    acc = 0.f; cur = nd;
                }
                acc += (c == 32) ? ewl[r] : msgl[r * 48 + c];
            }
            if (cur >= 0) {
                if (c == 32) {
                    bool interior = (startp[cur] >= e0) && (startp[cur + 1] <= e0 + 128);
                    if (interior) den[cur] = acc; else atomicAdd(den + cur, acc);
                } else {
                    atomicAdd(agg + cur * 80 + c, acc);
                }
            }
        }
    } else {
        // phase 1: S partial (w2 tail) — dual-writer, always atomicAdd
#pragma unroll
        for (int et = 0; et < 2; et++) {
            int le = el[et];
            float ew = ewl[le];
#pragma unroll
            for (int oh = 0; oh < 2; oh++)
#pragma unroll
                for (int r = 0; r < 4; r++)
                    msgl[le * 48 + oh * 16 + q4 * 4 + r] = msgS[oh][et][r] * ew;
        }
        __syncthreads();
        if (tid < 32) {
            int c = tid;
            int cur = dstl[0];
            float acc = 0.f;
            for (int r = 0; r < cnt; r++) {
                int nd = dstl[r];
                if (nd != cur) {
                    if (cur >= 0) atomicAdd(agg + cur * 80 + c, acc);
                    acc = 0.f; cur = nd;
                }
                acc += msgl[r * 48 + c];
            }
            if (cur >= 0) atomicAdd(agg + cur * 80 + c, acc);
        }
        __syncthreads();
        // phase 2: V channels — single-writer, interior-store
#pragma unroll
        for (int et = 0; et < 2; et++) {
            int le = el[et];
            float ew = ewl[le];
            float s0 = sh1l[le][0], s1 = sh1l[le][1], s2 = sh1l[le][2];
            float b4 = f4e[et];
#pragma unroll
            for (int r = 0; r < 4; r++) {
                int o = q4 * 4 + r;
                float qq = A3C * q3[et][r];
                msgl[le * 48 + o * 3 + 0] = (qq * s0 + b4 * qv[0][et][r]) * ew;
                msgl[le * 48 + o * 3 + 1] = (qq * s1 + b4 * qv[1][et][r]) * ew;
                msgl[le * 48 + o * 3 + 2] = (qq * s2 + b4 * qv[2][et][r]) * ew;
            }
        }
        __syncthreads();
        if (tid < 48) {
            int c = tid;
            int cur = dstl[0];
            float acc = 0.f;
            for (int r = 0; r < cnt; r++) {
                int nd = dstl[r];
                if (nd != cur) {
                    if (cur >= 0) {
                        bool interior = (startp[cur] >= e0) && (startp[cur + 1] <= e0 + 128);
                        float* p = agg + cur * 80 + 32 + c;
                        if (interior) *p = acc; else atomicAdd(p, acc);
                    }
                    acc = 0.f; cur = nd;
                }
                acc += msgl[r * 48 + c];
            }
            if (cur >= 0) {
                bool interior = (startp[cur] >= e0) && (startp[cur + 1] <= e0 + 128);
                float* p = agg + cur * 80 + 32 + c;
                if (interior) *p = acc; else atomicAdd(p, acc);
            }
        }
    }
}

// ---------------- K_update: per-node update (divides by den) --------------------
__global__ void k_update(
    const float* __restrict__ x, const float* __restrict__ xn,
    const float* __restrict__ agg, const float* __restrict__ den,
    const float* __restrict__ Ws, const float* __restrict__ Wv,
    const float* __restrict__ Us, const float* __restrict__ Uv,
    const float* __restrict__ Ss, const float* __restrict__ Sv,
    const float* __restrict__ rsp, float* __restrict__ out) {
    int n = blockIdx.x, t = threadIdx.x;
    __shared__ float ag[DD];
    __shared__ float xnl[DD];
    __shared__ float sg[NS];
    __shared__ float gt[NV];
    __shared__ float vg[48];
    float idv = 1.0f / fmaxf(den[n], 1e-8f);
    ag[t] = agg[n * DD + t] * idv;
    if (t < 16) ag[64 + t] = agg[n * DD + 64 + t] * idv;
    xnl[t] = xn[n * DD + t];
    if (t < 16) xnl[64 + t] = xn[n * DD + 64 + t];
    __syncthreads();
    const float iqs = 0.17677669529663687f;
    const float iqv = 0.25f;
    if (t < 48) {
        float acc = 0.f;
#pragma unroll
        for (int i = 0; i < NS; i++) acc += ag[i] * Ws[i * 48 + t];
        acc *= iqs;
        if (t < NS) sg[t] = silu_f(acc);
        else gt[t - NS] = sigm(acc);
    }
    __syncthreads();
    if (t < 48) {
        int o = t / 3, m = t - 3 * o;
        float acc = 0.f;
#pragma unroll
        for (int i = 0; i < NV; i++) acc += ag[NS + 3 * i + m] * Wv[i * NV + o];
        vg[t] = acc * iqv * gt[o];
    }
    __syncthreads();
    float rs = rsp[0];
    if (t < NS) {
        float us = 0.f, ss = 0.f;
#pragma unroll
        for (int i = 0; i < NS; i++) { us += sg[i] * Us[i * NS + t]; ss += xnl[i] * Ss[i * NS + t]; }
        out[n * DD + t] = x[n * DD + t] + rs * ((ss + us) * iqs);
    }
    if (t < 48) {
        int o = t / 3, m = t - 3 * o;
        float uv = 0.f, sv = 0.f;
#pragma unroll
        for (int i = 0; i < NV; i++) { uv += vg[3 * i + m] * Uv[i * NV + o]; sv += xnl[NS + 3 * i + m] * Sv[i * NV + o]; }
        out[n * DD + NS + t] = x[n * DD + NS + t] + rs * ((sv + uv) * iqv);
    }
}

extern "C" void kernel_launch(void* const* d_in, const int* in_sizes, int n_in,
                              void* d_out, int out_size, void* d_ws, size_t ws_size,
                              hipStream_t stream) {
    (void)in_sizes; (void)n_in; (void)out_size; (void)ws_size;
    const float* x    = (const float*)d_in[0];
    const int*   esrc = (const int*)d_in[1];
    const int*   edst = (const int*)d_in[2];
    const float* esh  = (const float*)d_in[3];
    const float* erbf = (const float*)d_in[4];
    const float* elen = (const float*)d_in[5];
    const float* nw   = (const float*)d_in[6];
    const float* nb   = (const float*)d_in[7];
    const float* mw1  = (const float*)d_in[8];
    const float* mb1  = (const float*)d_in[9];
    const float* mw2  = (const float*)d_in[10];
    const float* mb2  = (const float*)d_in[11];
    const float* mw3  = (const float*)d_in[12];
    const float* mb3  = (const float*)d_in[13];
    const float* gw1  = (const float*)d_in[14];
    const float* gb1  = (const float*)d_in[15];
    const float* gw2  = (const float*)d_in[16];
    const float* gb2  = (const float*)d_in[17];
    const float* Ws   = (const float*)d_in[18];
    const float* Wv   = (const float*)d_in[19];
    const float* Us   = (const float*)d_in[20];
    const float* Uv   = (const float*)d_in[21];
    const float* Ss   = (const float*)d_in[22];
    const float* Sv   = (const float*)d_in[23];
    const float* rsp  = (const float*)d_in[24];
    float* out = (float*)d_out;
    float* ws  = (float*)d_ws;

    // ws layout (float offsets); [0, 265600) is zeroed each launch.
    float* agg    = ws;                        // 256000
    float* den    = ws + 256000;               // 3200
    int*   hist   = (int*)(ws + 259200);       // 3200
    int*   cur    = (int*)(ws + 262400);       // 3200
    int*   startp = (int*)(ws + 265600);       // 3201
    int*   perm   = (int*)(ws + 268801);       // 50000 (pad to 318804)
    float* xn     = ws + 318804;               // 256000
    float* ewg    = ws + 574804;               // 50000
    __hip_bfloat16* h2b   = (__hip_bfloat16*)(ws + 624804);   // 6.4M bf16
    __hip_bfloat16* mw3f  = (__hip_bfloat16*)(ws + 3824804);  // 294912 bf16
    __hip_bfloat16* biasf = (__hip_bfloat16*)(ws + 3972260);  // 3072 bf16
    __hip_bfloat16* mw2f  = (__hip_bfloat16*)(ws + 3973796);  // 16384 bf16

    hipMemsetAsync(ws, 0, 265600 * sizeof(float), stream);    // agg+den+hist+cur
    k_prep0<<<8, 256, 0, stream>>>(mw2, mw2f);
    k_front<<<1923, 256, 0, stream>>>(erbf, elen, edst, mw1, mb1, gw1, gb1, gw2, gb2,
                                      mb2, mw2f, mw3, mb3, x, nw, nb,
                                      ewg, h2b, mw3f, biasf, xn, hist);
    k_scan<<<1, 256, 0, stream>>>(hist, startp);
    k_scatter<<<196, 256, 0, stream>>>(edst, startp, cur, perm);
    k_msg<<<782, 256, 0, stream>>>(xn, h2b, ewg, esrc, edst, perm, esh,
                                   mw3f, biasf, startp, agg, den);
    k_update<<<N_NODES, 64, 0, stream>>>(x, xn, agg, den, Ws, Wv, Us, Uv, Ss, Sv, rsp, out);
}

// Round 9
// 269.304 us; speedup vs baseline: 1.0478x; 1.0478x over previous
//
#include <hip/hip_runtime.h>
#include <hip/hip_bf16.h>
#include <math.h>

#define N_NODES 3200
#define E_EDGES 50000
#define RBFN 16
#define HID 128
#define NS 32
#define NV 16
#define DD 80
#define WNUM 2304
#define CUTF 5.0f
#define EPSF 1e-8f

#define A1C 0.125f                  // 1/sqrt(2*NS)
#define A2C 0.17677669529663687f    // 1/sqrt(2*NV)
#define A3C 0.125f
#define A4C 0.17677669529663687f
#define A2ISQ 0.10206207261596575f  // A2C / sqrt(3)

typedef __attribute__((ext_vector_type(4))) float f32x4;
typedef __attribute__((ext_vector_type(8))) short bf16x8;

__device__ __forceinline__ float sigm(float x) { return 1.0f / (1.0f + __expf(-x)); }
__device__ __forceinline__ float silu_f(float x) { return x * sigm(x); }

__device__ __forceinline__ short bf16r(float x) {
    union { float f; unsigned u; } v; v.f = x;
    unsigned r = (v.u + 0x7fffu + ((v.u >> 16) & 1u)) >> 16;
    return (short)r;
}
__device__ __forceinline__ float b2f(unsigned short s) {
    union { float f; unsigned u; } v; v.u = ((unsigned)s) << 16; return v.f;
}

// ---------------- CSR sort helpers ----------------------------------------------
__global__ void k_scan(const int* __restrict__ hist, int* __restrict__ start) {
    __shared__ int part[256];
    int t = threadIdx.x;
    int loc[13];
    int s = 0;
#pragma unroll
    for (int j = 0; j < 13; j++) {
        int idx = t * 13 + j;
        int v = (idx < N_NODES) ? hist[idx] : 0;
        loc[j] = s; s += v;
    }
    part[t] = s;
    __syncthreads();
    for (int off = 1; off < 256; off <<= 1) {
        int v = part[t];
        int add = (t >= off) ? part[t - off] : 0;
        __syncthreads();
        part[t] = v + add;
        __syncthreads();
    }
    int pre = (t == 0) ? 0 : part[t - 1];
#pragma unroll
    for (int j = 0; j < 13; j++) {
        int idx = t * 13 + j;
        if (idx < N_NODES) start[idx] = pre + loc[j];
    }
    if (t == 255) start[N_NODES] = part[255];
}

__global__ void k_scatter(const int* __restrict__ edst, const int* __restrict__ start,
                          int* __restrict__ cur, int* __restrict__ perm) {
    int e = blockIdx.x * 256 + threadIdx.x;
    if (e < E_EDGES) {
        int d = edst[e];
        int pos = start[d] + atomicAdd(&cur[d], 1);
        perm[pos] = e;
    }
}

// ---------------- K_prep0: mw2 -> frag-linear bf16 (must precede k_front) -------
__global__ void k_prep0(const float* __restrict__ mw2, __hip_bfloat16* __restrict__ mw2f) {
    __shared__ __hip_bfloat16 st[2048];
    int t = blockIdx.x, tid = threadIdx.x;
    for (int idx = tid; idx < 2048; idx += 256) {
        int k = idx >> 4, c = idx & 15;
        float v = mw2[k * HID + t * 16 + c];
        int kk = k >> 5, q4 = (k >> 3) & 3, j = k & 7;
        st[kk * 512 + (q4 * 16 + c) * 8 + j] = __float2bfloat16(v);
    }
    __syncthreads();
    ((bf16x8*)(mw2f + t * 2048))[tid] = ((const bf16x8*)st)[tid];
}

// ---------------- K_front: edge MLP (fused) + mw3 prep + norm + hist ------------
__global__ __launch_bounds__(256) void k_front(
    const float* __restrict__ rbf, const float* __restrict__ elen,
    const int* __restrict__ edst,
    const float* __restrict__ mw1, const float* __restrict__ mb1,
    const float* __restrict__ gw1, const float* __restrict__ gb1,
    const float* __restrict__ gw2, const float* __restrict__ gb2,
    const float* __restrict__ mb2, const __hip_bfloat16* __restrict__ mw2f,
    const float* __restrict__ mw3, const float* __restrict__ mb3,
    const float* __restrict__ x, const float* __restrict__ nw, const float* __restrict__ nb,
    float* __restrict__ ewg, __hip_bfloat16* __restrict__ h2b,
    __hip_bfloat16* __restrict__ mw3f, __hip_bfloat16* __restrict__ biasf,
    float* __restrict__ xn, int* __restrict__ hist) {
    __shared__ __align__(16) char smem[16640];
    int b = blockIdx.x, tid = threadIdx.x;
    if (b < 782) {
        __hip_bfloat16* h1l = (__hip_bfloat16*)smem;   // [64][128]
        int wid = __builtin_amdgcn_readfirstlane(tid >> 6);
        int lane = tid & 63;
        int base = b * 64;
        int eb = base + wid * 16;
        // ---- mlp1 (wave: 16 edges x 128 ch) ----
        {
            int c0 = lane, c1 = 64 + lane;
            float t0[16], t1[16], g0[16], g1[16];
            float b0 = mb1[c0], b1 = mb1[c1], gb0v = gb1[c0], gb1v = gb1[c1];
#pragma unroll
            for (int e = 0; e < 16; e++) { t0[e] = b0; t1[e] = b1; g0[e] = gb0v; g1[e] = gb1v; }
#pragma unroll
            for (int r = 0; r < RBFN; r++) {
                float w0 = mw1[r * HID + c0], w1 = mw1[r * HID + c1];
                float v0 = gw1[r * HID + c0], v1 = gw1[r * HID + c1];
#pragma unroll
                for (int e = 0; e < 16; e++) {
                    int ee = eb + e; if (ee >= E_EDGES) ee = E_EDGES - 1;
                    float rv = rbf[ee * RBFN + r];
                    t0[e] += rv * w0; t1[e] += rv * w1;
                    g0[e] += rv * v0; g1[e] += rv * v1;
                }
            }
            float q0 = gw2[c0], q1 = gw2[c1];
            float gb2v = gb2[0];
#pragma unroll
            for (int e = 0; e < 16; e++) {
                int le = wid * 16 + e;
                h1l[le * 128 + c0] = __float2bfloat16(silu_f(t0[e]));
                h1l[le * 128 + c1] = __float2bfloat16(silu_f(t1[e]));
                float p = silu_f(g0[e]) * q0 + silu_f(g1[e]) * q1;
                p += __shfl_xor(p, 1);  p += __shfl_xor(p, 2);  p += __shfl_xor(p, 4);
                p += __shfl_xor(p, 8);  p += __shfl_xor(p, 16); p += __shfl_xor(p, 32);
                if (lane == 0 && eb + e < E_EDGES) {
                    float len = elen[eb + e];
                    float cut = (len <= CUTF) ? 0.5f * (cosf(3.14159265358979f * len / CUTF) + 1.0f) : 0.f;
                    ewg[eb + e] = cut * sigm(p + gb2v);
                }
            }
        }
        __syncthreads();
        // ---- mlp2 (wave: 16 edges, MFMA vs mw2f) ----
        {
            int q4 = lane >> 4, l15 = lane & 15;
            int le = wid * 16 + l15;
            bf16x8 af[4];
#pragma unroll
            for (int kk = 0; kk < 4; kk++)
                af[kk] = *(const bf16x8*)(h1l + le * 128 + kk * 32 + q4 * 8);
            const f32x4 zf = {0.f, 0.f, 0.f, 0.f};
#pragma unroll
            for (int ct = 0; ct < 8; ct++) {
                f32x4 acc = zf;
#pragma unroll
                for (int kk = 0; kk < 4; kk++) {
                    bf16x8 bw = *(const bf16x8*)(mw2f + (ct * 4 + kk) * 512 + lane * 8);
                    acc = __builtin_amdgcn_mfma_f32_16x16x32_bf16(af[kk], bw, acc, 0, 0, 0);
                }
                float bias = mb2[ct * 16 + l15];
#pragma unroll
                for (int r = 0; r < 4; r++) {
                    int ge = base + wid * 16 + q4 * 4 + r;
                    if (ge < E_EDGES)
                        h2b[ge * HID + ct * 16 + l15] = __float2bfloat16(silu_f(acc[r] + bias));
                }
            }
        }
    } else if (b < 927) {
        int b2 = b - 782;
        __hip_bfloat16* st = (__hip_bfloat16*)smem;
        if (b2 < 144) {
            for (int idx = tid; idx < 2048; idx += 256) {
                int k = idx >> 4, c = idx & 15;
                float v = mw3[k * WNUM + b2 * 16 + c];
                int kk = k >> 5, q4 = (k >> 3) & 3, j = k & 7;
                st[kk * 512 + (q4 * 16 + c) * 8 + j] = __float2bfloat16(v);
            }
            __syncthreads();
            ((bf16x8*)(mw3f + b2 * 2048))[tid] = ((const bf16x8*)st)[tid];
        } else {
            for (int idx = tid; idx < 3072; idx += 256) {
                float val;
                if (idx < 1024) {
                    int oh = idx >> 9, l = (idx >> 3) & 63, j = idx & 7;
                    int o = oh * 16 + (l & 15), i = (l >> 4) * 8 + j;
                    val = mb3[i * 32 + o];
                } else if (idx < 2048) {
                    int t = idx - 1024;
                    int oh = t >> 9, l = (t >> 3) & 63, j = t & 7;
                    int o = oh * 16 + (l & 15), i = (l >> 4) * 8 + j;
                    val = (i < 16) ? mb3[1024 + i * 32 + o] : 0.f;
                } else if (idx < 2560) {
                    int t = idx - 2048;
                    int l = t >> 3, j = t & 7;
                    int o = l & 15, i = (l >> 4) * 8 + j;
                    val = mb3[1536 + i * 16 + o];
                } else {
                    int t = idx - 2560;
                    int l = t >> 3, j = t & 7;
                    int o = l & 15, i = (l >> 4) * 8 + j;
                    val = (i < 16) ? mb3[2048 + i * 16 + o] : 0.f;
                }
                biasf[idx] = __float2bfloat16(val);
            }
        }
    } else if (b < 1727) {
        // irrep norm: 4 nodes per block
        float* row = (float*)smem;   // [4][80]
        int sub = tid >> 6, t = tid & 63;
        int n = (b - 927) * 4 + sub;
        float* rw = row + sub * 80;
        const float* xr = x + n * DD;
        rw[t] = xr[t];
        if (t < 16) rw[64 + t] = xr[64 + t];
        __syncthreads();
        float mean = 0.f;
#pragma unroll
        for (int i = 0; i < NS; i++) mean += rw[i];
        mean *= (1.0f / NS);
        float var = 0.f;
#pragma unroll
        for (int i = 0; i < NS; i++) { float d = rw[i] - mean; var += d * d; }
        var *= (1.0f / NS);
        float inv = rsqrtf(var + EPSF);
        if (t < NS) xn[n * DD + t] = (rw[t] - mean) * inv * nw[t] + nb[t];
        if (t < 48) {
            int j = t / 3;
            float v0 = rw[NS + 3 * j], v1 = rw[NS + 3 * j + 1], v2 = rw[NS + 3 * j + 2];
            float rms = sqrtf((v0 * v0 + v1 * v1 + v2 * v2) * (1.0f / 3.0f) + EPSF);
            xn[n * DD + NS + t] = rw[NS + t] / rms * nw[NS + t] + nb[NS + t];
        }
    } else {
        int e = (b - 1727) * 256 + tid;
        if (e < E_EDGES) atomicAdd(&hist[edst[e]], 1);
    }
}

// -------- K_msg v9: no-barrier direct-load GEMM, 64 edges/wave, role split ------
// Grid = 391 groups (128 edges) x 2 roles = 782 blocks x 128 thr (2 waves).
// Wave owns 64 edges (4 MFMA B-tiles). Per-wave traffic 288 KB -> 450 MB total
// (R4 ran this structure at the 8.3 TB/s L2-broadcast ceiling with 900 MB).
// roleA: chunks 0..48 (w1+w2 -> S channels + den), only msgS live (~180 VGPR).
// roleB: chunks 48..72 (w3+w4 -> V channels), only q3/qv live (~210 VGPR).
// Loops duplicated per role so accumulator sets are never simultaneously live.
__global__ __launch_bounds__(128) void k_msg(
    const float* __restrict__ xn, const __hip_bfloat16* __restrict__ h2b,
    const float* __restrict__ ewg, const int* __restrict__ esrc,
    const int* __restrict__ edst, const int* __restrict__ perm,
    const float* __restrict__ esh,
    const __hip_bfloat16* __restrict__ mw3f, const __hip_bfloat16* __restrict__ biasf,
    const int* __restrict__ startp, float* __restrict__ agg, float* __restrict__ den) {
    __shared__ __align__(16) char pool[29696];
    unsigned short (*xng)[82]  = (unsigned short(*)[82])(pool);          // 20992 B
    unsigned short (*innr)[16] = (unsigned short(*)[16])(pool + 20992);  // 4096 B
    float (*sh1l)[4] = (float(*)[4])(pool + 25088);                      // 2048 B
    float* sh0l = (float*)(pool + 27136);
    float* ewl  = (float*)(pool + 27648);
    int* dstl   = (int*)(pool + 28160);
    int* srcl   = (int*)(pool + 28672);
    int* gel    = (int*)(pool + 29184);
    float* msgl = (float*)pool;   // [128][48] overlay = 24576 B (epilogue only)

    const int tid = threadIdx.x;
    const int wid = __builtin_amdgcn_readfirstlane(tid >> 6);
    const int lane = tid & 63;
    const int q4 = lane >> 4;
    const int l15 = lane & 15;
    const int ib = q4 * 8;
    const int role = blockIdx.x & 1;
    const int e0 = (blockIdx.x >> 1) * 128;

    if (tid < 128) {
        int slot = e0 + tid;
        bool v = slot < E_EDGES;
        int ge = v ? perm[slot] : 0;
        gel[tid] = ge;
        srcl[tid] = esrc[ge];
        dstl[tid] = v ? edst[ge] : -1;
        ewl[tid] = v ? ewg[ge] : 0.f;
        sh0l[tid] = esh[ge * 4];
        sh1l[tid][0] = esh[ge * 4 + 1];
        sh1l[tid][1] = esh[ge * 4 + 2];
        sh1l[tid][2] = esh[ge * 4 + 3];
    }
    __syncthreads();
    for (int idx = tid; idx < 128 * 80; idx += 128) {
        int e = idx / 80, q = idx - e * 80;
        xng[e][q] = (unsigned short)bf16r(xn[srcl[e] * 80 + q]);
    }
    __syncthreads();
    for (int idx = tid; idx < 128 * 16; idx += 128) {
        int e = idx >> 4, i = idx & 15;
        float d = b2f(xng[e][32 + 3 * i]) * sh1l[e][0]
                + b2f(xng[e][32 + 3 * i + 1]) * sh1l[e][1]
                + b2f(xng[e][32 + 3 * i + 2]) * sh1l[e][2];
        innr[e][i] = (unsigned short)bf16r(A2ISQ * d);
    }
    __syncthreads();

    // ---------------- per-wave B-fragments: 4 edge-tiles of 16 ------------------
    int el[4];
#pragma unroll
    for (int et = 0; et < 4; et++) el[et] = wid * 64 + et * 16 + l15;
    bf16x8 hfr[4][4];
#pragma unroll
    for (int et = 0; et < 4; et++) {
        int ge = gel[el[et]];
        const __hip_bfloat16* hr = h2b + ge * HID;
#pragma unroll
        for (int kk = 0; kk < 4; kk++)
            hfr[et][kk] = *(const bf16x8*)(hr + kk * 32 + ib);
    }
    const f32x4 zf = {0.f, 0.f, 0.f, 0.f};
    const bf16x8* gp = (const bf16x8*)mw3f;   // chunk n at gp + n*512; lane frag f*64+lane
    int cnt = E_EDGES - e0; if (cnt > 128) cnt = 128;

    if (role == 0) {
        // =================== roleA: chunks 0..48 -> S + den =====================
        float f1[4];
        f32x4 msgS[2][4];
#pragma unroll
        for (int et = 0; et < 4; et++) {
            f1[et] = A1C * sh0l[el[et]];
            // S bias via MFMA (added exactly once)
            bf16x8 p18, p28;
#pragma unroll
            for (int j = 0; j < 8; j++) {
                p18[j] = bf16r(b2f(xng[el[et]][ib + j]) * f1[et]);
                p28[j] = (ib + j < 16) ? (short)innr[el[et]][ib + j] : (short)0;
            }
            bf16x8 ba1a = *(const bf16x8*)(biasf + lane * 8);
            bf16x8 ba1b = *(const bf16x8*)(biasf + 512 + lane * 8);
            bf16x8 ba2a = *(const bf16x8*)(biasf + 1024 + lane * 8);
            bf16x8 ba2b = *(const bf16x8*)(biasf + 1536 + lane * 8);
            f32x4 a0 = __builtin_amdgcn_mfma_f32_16x16x32_bf16(ba1a, p18, zf, 0, 0, 0);
            msgS[0][et] = __builtin_amdgcn_mfma_f32_16x16x32_bf16(ba2a, p28, a0, 0, 0, 0);
            f32x4 a1 = __builtin_amdgcn_mfma_f32_16x16x32_bf16(ba1b, p18, zf, 0, 0, 0);
            msgS[1][et] = __builtin_amdgcn_mfma_f32_16x16x32_bf16(ba2b, p28, a1, 0, 0, 0);
        }
        auto computeA = [&](int n, bf16x8 (&A)[8]) {
            f32x4 acc[2][4];
#pragma unroll
            for (int half = 0; half < 2; half++)
#pragma unroll
                for (int et = 0; et < 4; et++) acc[half][et] = zf;
#pragma unroll
            for (int half = 0; half < 2; half++)
#pragma unroll
                for (int kk = 0; kk < 4; kk++)
#pragma unroll
                    for (int et = 0; et < 4; et++)
                        acc[half][et] = __builtin_amdgcn_mfma_f32_16x16x32_bf16(
                            A[half * 4 + kk], hfr[et][kk], acc[half][et], 0, 0, 0);
            float p[4];
            if (n < 32) {
#pragma unroll
                for (int et = 0; et < 4; et++) p[et] = f1[et] * b2f(xng[el[et]][n]);
            } else {
#pragma unroll
                for (int et = 0; et < 4; et++) p[et] = b2f(innr[el[et]][n - 32]);
            }
#pragma unroll
            for (int half = 0; half < 2; half++)
#pragma unroll
                for (int et = 0; et < 4; et++)
#pragma unroll
                    for (int r = 0; r < 4; r++)
                        msgS[half][et][r] += p[et] * acc[half][et][r];
        };
        bf16x8 A0[8], A1[8];
#pragma unroll
        for (int f = 0; f < 8; f++) A0[f] = gp[f * 64 + lane];
        for (int n = 0; n < 48; n += 2) {
            const bf16x8* g1 = gp + (n + 1) * 512;
#pragma unroll
            for (int f = 0; f < 8; f++) A1[f] = g1[f * 64 + lane];
            computeA(n, A0);
            if (n + 2 < 48) {
                const bf16x8* g2 = gp + (n + 2) * 512;
#pragma unroll
                for (int f = 0; f < 8; f++) A0[f] = g2[f * 64 + lane];
            }
            computeA(n + 1, A1);
        }
        // ---- epilogue A: S channels + den (single-writer) ----
        __syncthreads();
#pragma unroll
        for (int et = 0; et < 4; et++) {
            int le = el[et];
            float ew = ewl[le];
#pragma unroll
            for (int oh = 0; oh < 2; oh++)
#pragma unroll
                for (int r = 0; r < 4; r++)
                    msgl[le * 48 + oh * 16 + q4 * 4 + r] = msgS[oh][et][r] * ew;
        }
        __syncthreads();
        if (tid < 33) {
            int c = tid;
            int cur = dstl[0];
            float acc = 0.f;
            for (int r = 0; r < cnt; r++) {
                int nd = dstl[r];
                if (nd != cur) {
                    if (cur >= 0) {
                        bool interior = (startp[cur] >= e0) && (startp[cur + 1] <= e0 + 128);
                        float* p = (c == 32) ? (den + cur) : (agg + cur * 80 + c);
                        if (interior) *p = acc; else atomicAdd(p, acc);
                    }
                    acc = 0.f; cur = nd;
                }
                acc += (c == 32) ? ewl[r] : msgl[r * 48 + c];
            }
            if (cur >= 0) {
                bool interior = (startp[cur] >= e0) && (startp[cur + 1] <= e0 + 128);
                float* p = (c == 32) ? (den + cur) : (agg + cur * 80 + c);
                if (interior) *p = acc; else atomicAdd(p, acc);
            }
        }
    } else {
        // =================== roleB: chunks 48..72 -> V channels =================
        float f4e[4];
        f32x4 q3[4], qv[3][4];
#pragma unroll
        for (int et = 0; et < 4; et++) {
            f4e[et] = A4C * sh0l[el[et]];
            // V bias via MFMA
            bf16x8 xs8;
#pragma unroll
            for (int j = 0; j < 8; j++) xs8[j] = (short)xng[el[et]][ib + j];
            bf16x8 ba3 = *(const bf16x8*)(biasf + 2048 + lane * 8);
            bf16x8 ba4 = *(const bf16x8*)(biasf + 2560 + lane * 8);
            q3[et] = __builtin_amdgcn_mfma_f32_16x16x32_bf16(ba3, xs8, zf, 0, 0, 0);
#pragma unroll
            for (int m = 0; m < 3; m++) {
                bf16x8 t8;
#pragma unroll
                for (int j = 0; j < 8; j++) {
                    int i = ib + j;
                    t8[j] = (i < 16) ? (short)xng[el[et]][32 + 3 * i + m] : (short)0;
                }
                qv[m][et] = __builtin_amdgcn_mfma_f32_16x16x32_bf16(ba4, t8, zf, 0, 0, 0);
            }
        }
        auto computeB = [&](int n, bf16x8 (&A)[8]) {
            f32x4 acc[2][4];
#pragma unroll
            for (int half = 0; half < 2; half++)
#pragma unroll
                for (int et = 0; et < 4; et++) acc[half][et] = zf;
#pragma unroll
            for (int half = 0; half < 2; half++)
#pragma unroll
                for (int kk = 0; kk < 4; kk++)
#pragma unroll
                    for (int et = 0; et < 4; et++)
                        acc[half][et] = __builtin_amdgcn_mfma_f32_16x16x32_bf16(
                            A[half * 4 + kk], hfr[et][kk], acc[half][et], 0, 0, 0);
            if (n < 64) {          // w3 -> q3
#pragma unroll
                for (int half = 0; half < 2; half++) {
                    int i = 2 * (n - 48) + half;
                    float p[4];
#pragma unroll
                    for (int et = 0; et < 4; et++) p[et] = b2f(xng[el[et]][i]);
#pragma unroll
                    for (int et = 0; et < 4; et++)
#pragma unroll
                        for (int r = 0; r < 4; r++)
                            q3[et][r] += p[et] * acc[half][et][r];
                }
            } else {               // w4 -> qv
#pragma unroll
                for (int half = 0; half < 2; half++) {
                    int i = 2 * (n - 64) + half;
#pragma unroll
                    for (int m = 0; m < 3; m++) {
                        float p[4];
#pragma unroll
                        for (int et = 0; et < 4; et++) p[et] = b2f(xng[el[et]][32 + 3 * i + m]);
#pragma unroll
                        for (int et = 0; et < 4; et++)
#pragma unroll
                            for (int r = 0; r < 4; r++)
                                qv[m][et][r] += p[et] * acc[half][et][r];
                    }
                }
            }
        };
        bf16x8 A0[8], A1[8];
#pragma unroll
        for (int f = 0; f < 8; f++) A0[f] = gp[48 * 512 + f * 64 + lane];
        for (int n = 48; n < 72; n += 2) {
            const bf16x8* g1 = gp + (n + 1) * 512;
#pragma unroll
            for (int f = 0; f < 8; f++) A1[f] = g1[f * 64 + lane];
            computeB(n, A0);
            if (n + 2 < 72) {
                const bf16x8* g2 = gp + (n + 2) * 512;
#pragma unroll
                for (int f = 0; f < 8; f++) A0[f] = g2[f * 64 + lane];
            }
            computeB(n + 1, A1);
        }
        // ---- epilogue B: V channels (single-writer) ----
        __syncthreads();
#pragma unroll
        for (int et = 0; et < 4; et++) {
            int le = el[et];
            float ew = ewl[le];
            float s0 = sh1l[le][0], s1 = sh1l[le][1], s2 = sh1l[le][2];
            float b4 = f4e[et];
#pragma unroll
            for (int r = 0; r < 4; r++) {
                int o = q4 * 4 + r;
                float qq = A3C * q3[et][r];
                msgl[le * 48 + o * 3 + 0] = (qq * s0 + b4 * qv[0][et][r]) * ew;
                msgl[le * 48 + o * 3 + 1] = (qq * s1 + b4 * qv[1][et][r]) * ew;
                msgl[le * 48 + o * 3 + 2] = (qq * s2 + b4 * qv[2][et][r]) * ew;
            }
        }
        __syncthreads();
        if (tid < 48) {
            int c = tid;
            int cur = dstl[0];
            float acc = 0.f;
            for (int r = 0; r < cnt; r++) {
                int nd = dstl[r];
                if (nd != cur) {
                    if (cur >= 0) {
                        bool interior = (startp[cur] >= e0) && (startp[cur + 1] <= e0 + 128);
                        float* p = agg + cur * 80 + 32 + c;
                        if (interior) *p = acc; else atomicAdd(p, acc);
                    }
                    acc = 0.f; cur = nd;
                }
                acc += msgl[r * 48 + c];
            }
            if (cur >= 0) {
                bool interior = (startp[cur] >= e0) && (startp[cur + 1] <= e0 + 128);
                float* p = agg + cur * 80 + 32 + c;
                if (interior) *p = acc; else atomicAdd(p, acc);
            }
        }
    }
}

// ---------------- K_update: per-node update (divides by den) --------------------
__global__ void k_update(
    const float* __restrict__ x, const float* __restrict__ xn,
    const float* __restrict__ agg, const float* __restrict__ den,
    const float* __restrict__ Ws, const float* __restrict__ Wv,
    const float* __restrict__ Us, const float* __restrict__ Uv,
    const float* __restrict__ Ss, const float* __restrict__ Sv,
    const float* __restrict__ rsp, float* __restrict__ out) {
    int n = blockIdx.x, t = threadIdx.x;
    __shared__ float ag[DD];
    __shared__ float xnl[DD];
    __shared__ float sg[NS];
    __shared__ float gt[NV];
    __shared__ float vg[48];
    float idv = 1.0f / fmaxf(den[n], 1e-8f);
    ag[t] = agg[n * DD + t] * idv;
    if (t < 16) ag[64 + t] = agg[n * DD + 64 + t] * idv;
    xnl[t] = xn[n * DD + t];
    if (t < 16) xnl[64 + t] = xn[n * DD + 64 + t];
    __syncthreads();
    const float iqs = 0.17677669529663687f;
    const float iqv = 0.25f;
    if (t < 48) {
        float acc = 0.f;
#pragma unroll
        for (int i = 0; i < NS; i++) acc += ag[i] * Ws[i * 48 + t];
        acc *= iqs;
        if (t < NS) sg[t] = silu_f(acc);
        else gt[t - NS] = sigm(acc);
    }
    __syncthreads();
    if (t < 48) {
        int o = t / 3, m = t - 3 * o;
        float acc = 0.f;
#pragma unroll
        for (int i = 0; i < NV; i++) acc += ag[NS + 3 * i + m] * Wv[i * NV + o];
        vg[t] = acc * iqv * gt[o];
    }
    __syncthreads();
    float rs = rsp[0];
    if (t < NS) {
        float us = 0.f, ss = 0.f;
#pragma unroll
        for (int i = 0; i < NS; i++) { us += sg[i] * Us[i * NS + t]; ss += xnl[i] * Ss[i * NS + t]; }
        out[n * DD + t] = x[n * DD + t] + rs * ((ss + us) * iqs);
    }
    if (t < 48) {
        int o = t / 3, m = t - 3 * o;
        float uv = 0.f, sv = 0.f;
#pragma unroll
        for (int i = 0; i < NV; i++) { uv += vg[3 * i + m] * Uv[i * NV + o]; sv += xnl[NS + 3 * i + m] * Sv[i * NV + o]; }
        out[n * DD + NS + t] = x[n * DD + NS + t] + rs * ((sv + uv) * iqv);
    }
}

extern "C" void kernel_launch(void* const* d_in, const int* in_sizes, int n_in,
                              void* d_out, int out_size, void* d_ws, size_t ws_size,
                              hipStream_t stream) {
    (void)in_sizes; (void)n_in; (void)out_size; (void)ws_size;
    const float* x    = (const float*)d_in[0];
    const int*   esrc = (const int*)d_in[1];
    const int*   edst = (const int*)d_in[2];
    const float* esh  = (const float*)d_in[3];
    const float* erbf = (const float*)d_in[4];
    const float* elen = (const float*)d_in[5];
    const float* nw   = (const float*)d_in[6];
    const float* nb   = (const float*)d_in[7];
    const float* mw1  = (const float*)d_in[8];
    const float* mb1  = (const float*)d_in[9];
    const float* mw2  = (const float*)d_in[10];
    const float* mb2  = (const float*)d_in[11];
    const float* mw3  = (const float*)d_in[12];
    const float* mb3  = (const float*)d_in[13];
    const float* gw1  = (const float*)d_in[14];
    const float* gb1  = (const float*)d_in[15];
    const float* gw2  = (const float*)d_in[16];
    const float* gb2  = (const float*)d_in[17];
    const float* Ws   = (const float*)d_in[18];
    const float* Wv   = (const float*)d_in[19];
    const float* Us   = (const float*)d_in[20];
    const float* Uv   = (const float*)d_in[21];
    const float* Ss   = (const float*)d_in[22];
    const float* Sv   = (const float*)d_in[23];
    const float* rsp  = (const float*)d_in[24];
    float* out = (float*)d_out;
    float* ws  = (float*)d_ws;

    // ws layout (float offsets); [0, 265600) is zeroed each launch.
    float* agg    = ws;                        // 256000
    float* den    = ws + 256000;               // 3200
    int*   hist   = (int*)(ws + 259200);       // 3200
    int*   cur    = (int*)(ws + 262400);       // 3200
    int*   startp = (int*)(ws + 265600);       // 3201
    int*   perm   = (int*)(ws + 268801);       // 50000 (pad to 318804)
    float* xn     = ws + 318804;               // 256000
    float* ewg    = ws + 574804;               // 50000
    __hip_bfloat16* h2b   = (__hip_bfloat16*)(ws + 624804);   // 6.4M bf16
    __hip_bfloat16* mw3f  = (__hip_bfloat16*)(ws + 3824804);  // 294912 bf16
    __hip_bfloat16* biasf = (__hip_bfloat16*)(ws + 3972260);  // 3072 bf16
    __hip_bfloat16* mw2f  = (__hip_bfloat16*)(ws + 3973796);  // 16384 bf16

    hipMemsetAsync(ws, 0, 265600 * sizeof(float), stream);    // agg+den+hist+cur
    k_prep0<<<8, 256, 0, stream>>>(mw2, mw2f);
    k_front<<<1923, 256, 0, stream>>>(erbf, elen, edst, mw1, mb1, gw1, gb1, gw2, gb2,
                                      mb2, mw2f, mw3, mb3, x, nw, nb,
                                      ewg, h2b, mw3f, biasf, xn, hist);
    k_scan<<<1, 256, 0, stream>>>(hist, startp);
    k_scatter<<<196, 256, 0, stream>>>(edst, startp, cur, perm);
    k_msg<<<782, 128, 0, stream>>>(xn, h2b, ewg, esrc, edst, perm, esh,
                                   mw3f, biasf, startp, agg, den);
    k_update<<<N_NODES, 64, 0, stream>>>(x, xn, agg, den, Ws, Wv, Us, Uv, Ss, Sv, rsp, out);
}